// Round 8
// baseline (588.673 us; speedup 1.0000x reference)
//
#include <hip/hip_runtime.h>
#include <cstdint>

#define B_ 16
#define N_ 4096
#define C_ 1024
#define K_ 64

typedef float vf4 __attribute__((ext_vector_type(4)));

// ws float-index layout
#define WS_WBAR   0                    // 1024 f32
#define WS_BBAR   1024                 // 1 f32
#define WS_SCORES 2048                 // B*N f32
#define WS_CNT    (WS_SCORES + B_*N_)  // B u32 per-batch completion counters

// ---- wbar: 64 blocks x 16 columns; block 64: bbar + counter zero ----
__global__ __launch_bounds__(256) void wbar_kernel(const float* __restrict__ W,
                                                   const float* __restrict__ b,
                                                   float* __restrict__ ws) {
    int j = blockIdx.x, t = threadIdx.x;
    if (j == 64) {
        if (t < B_) ((unsigned*)(ws + WS_CNT))[t] = 0u;   // re-zero every launch
        float4 bv = ((const float4*)b)[t];
        float sb = bv.x + bv.y + bv.z + bv.w;
        for (int off = 32; off; off >>= 1) sb += __shfl_xor(sb, off);
        __shared__ float red[4];
        if ((t & 63) == 0) red[t >> 6] = sb;
        __syncthreads();
        if (t == 0) ws[WS_BBAR] = (red[0] + red[1] + red[2] + red[3]) * (1.0f / C_);
        return;
    }
    int ci = t & 15, dr = t >> 4;                    // 16 col x 16 rowgroups
    int c = j * 16 + ci;
    float s = 0.f;
#pragma unroll 8
    for (int k = 0; k < 64; ++k)
        s += W[(size_t)(dr * 64 + k) * C_ + c];
    __shared__ float sd[16][16];
    sd[dr][ci] = s;
    __syncthreads();
    if (t < 16) {
        float acc = 0.f;
#pragma unroll
        for (int d = 0; d < 16; ++d) acc += sd[d][t];
        ws[WS_WBAR + j * 16 + t] = acc * (1.0f / C_);
    }
}

// sortable-uint mapping for f32 (monotonic)
__device__ __forceinline__ unsigned su_(float f) {
    unsigned u = __float_as_uint(f);
    return (u & 0x80000000u) ? ~u : (u | 0x80000000u);
}
__device__ __forceinline__ float isu_(unsigned u) {
    unsigned v = (u & 0x80000000u) ? (u ^ 0x80000000u) : ~u;
    return __uint_as_float(v);
}

// ---- fused: scores (all blocks) + last-4-blocks-per-batch select/gather ----
__global__ __launch_bounds__(512) void scores_topk_kernel(const float* __restrict__ x,
                                                          float* ws,
                                                          float* __restrict__ out,
                                                          float* __restrict__ mask_out) {
    __shared__ unsigned hist[4096];                 // 16 KB
    __shared__ unsigned long long cand[4096];       // 32 KB
    __shared__ float redm[8], redd[8];
    __shared__ unsigned scnt, sold;
    __shared__ int sbin;
    __shared__ int   li[K_];
    __shared__ float la[K_];
    __shared__ float gsum[256];

    int t = threadIdx.x;
    int wave = t >> 6, lane = t & 63;
    int blk = blockIdx.x;
    int b = blk >> 9;                                // 512 blocks per batch

    // ---- scores phase: one wave per row ----
    const float4* wb4 = (const float4*)(ws + WS_WBAR);
    float4 wv0 = wb4[0 * 64 + lane];
    float4 wv1 = wb4[1 * 64 + lane];
    float4 wv2 = wb4[2 * 64 + lane];
    float4 wv3 = wb4[3 * 64 + lane];
    float bbar = ws[WS_BBAR];
    int row = blk * 8 + wave;
    const vf4* x4 = (const vf4*)x;
    vf4 xv0 = __builtin_nontemporal_load(x4 + (size_t)row * 256 + 0 * 64 + lane);
    vf4 xv1 = __builtin_nontemporal_load(x4 + (size_t)row * 256 + 1 * 64 + lane);
    vf4 xv2 = __builtin_nontemporal_load(x4 + (size_t)row * 256 + 2 * 64 + lane);
    vf4 xv3 = __builtin_nontemporal_load(x4 + (size_t)row * 256 + 3 * 64 + lane);
    float acc = xv0.x * wv0.x + xv0.y * wv0.y + xv0.z * wv0.z + xv0.w * wv0.w
              + xv1.x * wv1.x + xv1.y * wv1.y + xv1.z * wv1.z + xv1.w * wv1.w
              + xv2.x * wv2.x + xv2.y * wv2.y + xv2.z * wv2.z + xv2.w * wv2.w
              + xv3.x * wv3.x + xv3.y * wv3.y + xv3.z * wv3.z + xv3.w * wv3.w;
    for (int off = 32; off; off >>= 1) acc += __shfl_xor(acc, off);
    if (lane == 0) ws[WS_SCORES + row] = acc + bbar;

    __syncthreads();                                 // block stores drained (vmcnt)
    if (t == 0) {
        __threadfence();                             // publish stores device-wide
        sold = atomicAdd((unsigned*)(ws + WS_CNT) + b, 1u);
    }
    __syncthreads();                                 // sold visible to block
    if (sold < 508u) return;                         // not a selector block
    int cc = (int)(sold - 508u);                     // 0..3

    if (t == 0)                                      // wait for full batch
        while (atomicAdd((unsigned*)(ws + WS_CNT) + b, 0u) < 512u) {}
    __syncthreads();
    __threadfence();                                 // acquire: fresh score reads

    // ---- select phase (512 threads): thread owns idx i*2048 + 4t + e ----
    const float* srow = ws + WS_SCORES + b * N_;
    float v[8];
#pragma unroll
    for (int i = 0; i < 2; ++i) {
        float4 v4 = ((const float4*)srow)[i * 512 + t];
        v[i * 4 + 0] = v4.x; v[i * 4 + 1] = v4.y;
        v[i * 4 + 2] = v4.z; v[i * 4 + 3] = v4.w;
    }
#pragma unroll
    for (int i = 0; i < 2; ++i)
        ((uint4*)hist)[i * 512 + t] = make_uint4(0u, 0u, 0u, 0u);
    if (t == 0) scnt = 0;

    // batch max
    float m = v[0];
#pragma unroll
    for (int e = 1; e < 8; ++e) m = fmaxf(m, v[e]);
    for (int off = 32; off; off >>= 1) m = fmaxf(m, __shfl_xor(m, off));
    if (lane == 0) redm[wave] = m;
    __syncthreads();                                 // hist zeroed + redm ready
    m = redm[0];
#pragma unroll
    for (int i = 1; i < 8; ++i) m = fmaxf(m, redm[i]);

    // softmax denominator over ALL N
    float dsum = 0.f;
#pragma unroll
    for (int e = 0; e < 8; ++e) dsum += expf(v[e] - m);
    for (int off = 32; off; off >>= 1) dsum += __shfl_xor(dsum, off);
    if (lane == 0) redd[wave] = dsum;

    // histogram of top-12 bits of sortable key
#pragma unroll
    for (int e = 0; e < 8; ++e) atomicAdd(&hist[su_(v[e]) >> 20], 1u);
    __syncthreads();                                 // hist + redd ready
    float denom = redd[0];
#pragma unroll
    for (int i = 1; i < 8; ++i) denom += redd[i];

    // wave 0: suffix scan over 4096 bins for the rank-64 threshold bin
    if (wave == 0) {
        int base = lane * 64;
        unsigned s = 0;
        for (int j = 0; j < 64; ++j) s += hist[base + j];
        unsigned suf = s;
        for (int off = 1; off < 64; off <<= 1) {
            unsigned o = __shfl_down(suf, off);
            if (lane + off < 64) suf += o;
        }
        unsigned above = suf - s;
        if (above < (unsigned)K_ && above + s >= (unsigned)K_) {
            unsigned run = above;
            for (int j = 63; j >= 0; --j) {
                unsigned c = hist[base + j];
                if (run < (unsigned)K_ && run + c >= (unsigned)K_) sbin = base + j;
                run += c;
            }
        }
    }
    __syncthreads();                                 // sbin ready
    int Bn = sbin;

    // collect candidates (keys unique: idx in low bits)
#pragma unroll
    for (int i = 0; i < 2; ++i) {
#pragma unroll
        for (int e = 0; e < 4; ++e) {
            unsigned k32 = su_(v[i * 4 + e]);
            if ((int)(k32 >> 20) >= Bn) {
                unsigned idx = (unsigned)(i * 2048 + 4 * t + e);
                unsigned p = atomicAdd(&scnt, 1u);
                cand[p] = ((unsigned long long)k32 << 32) |
                          (unsigned long long)(0xFFFFFFFFu - idx);
            }
        }
    }
    // zero this selector's 1024-entry mask slice
#pragma unroll
    for (int i = 0; i < 2; ++i)
        mask_out[b * N_ + cc * 1024 + i * 512 + t] = 0.0f;
    __syncthreads();                                 // cand/scnt ready

    unsigned mc = scnt;
    for (unsigned i = t; i < mc; i += 512) {
        unsigned long long ki = cand[i];
        unsigned r = 0;
        for (unsigned j = 0; j < mc; ++j) r += (cand[j] > ki) ? 1u : 0u;
        if (r < (unsigned)K_) {                      // exact rank; tie -> lower idx
            unsigned widx = 0xFFFFFFFFu - (unsigned)(ki & 0xFFFFFFFFu);
            float sc = isu_((unsigned)(ki >> 32));
            li[r] = (int)widx;
            la[r] = expf(sc - m) / denom;
            if ((int)(widx >> 10) == cc)             // winner in this mask slice
                mask_out[b * N_ + widx] = 1.0f;
        }
    }
    __syncthreads();                                 // li/la ready

    // gather this selector's 256-col out slice; rows split across thread halves
    int col = cc * 256 + (t & 255);
    int rh = t >> 8;
    float ga = 0.f;
#pragma unroll 8
    for (int r = rh * 32; r < rh * 32 + 32; ++r)
        ga += la[r] * x[(size_t)(b * N_ + li[r]) * C_ + col];
    if (rh) gsum[t & 255] = ga;
    __syncthreads();
    if (!rh) out[b * C_ + col] = ga + gsum[t];
}

extern "C" void kernel_launch(void* const* d_in, const int* in_sizes, int n_in,
                              void* d_out, int out_size, void* d_ws, size_t ws_size,
                              hipStream_t stream) {
    const float* x = (const float*)d_in[0];   // (B,N,C) f32
    const float* W = (const float*)d_in[1];   // (C,C) f32
    const float* b = (const float*)d_in[2];   // (C,) f32
    float* out  = (float*)d_out;              // (B,C) then (B,N) mask
    float* mask = out + B_ * C_;
    float* ws   = (float*)d_ws;

    wbar_kernel       <<<65,          256, 0, stream>>>(W, b, ws);
    scores_topk_kernel<<<B_ * N_ / 8, 512, 0, stream>>>(x, ws, out, mask);
}

// Round 9
// 66.039 us; speedup vs baseline: 8.9140x; 8.9140x over previous
//
#include <hip/hip_runtime.h>
#include <cstdint>

#define B_ 16
#define N_ 4096
#define C_ 1024
#define K_ 64

typedef float vf4 __attribute__((ext_vector_type(4)));

// ws float-index layout
#define WS_WBAR   0                    // 1024 f32
#define WS_BBAR   1024                 // 1 f32
#define WS_SCORES 2048                 // B*N f32

// ---- wbar in one kernel: 64 blocks x 16 columns each; block 64: bbar ----
__global__ __launch_bounds__(256) void wbar_kernel(const float* __restrict__ W,
                                                   const float* __restrict__ b,
                                                   float* __restrict__ ws) {
    int j = blockIdx.x, t = threadIdx.x;
    if (j == 64) {                                   // bbar = mean(b)
        float4 bv = ((const float4*)b)[t];
        float sb = bv.x + bv.y + bv.z + bv.w;
        for (int off = 32; off; off >>= 1) sb += __shfl_xor(sb, off);
        __shared__ float red[4];
        if ((t & 63) == 0) red[t >> 6] = sb;
        __syncthreads();
        if (t == 0) ws[WS_BBAR] = (red[0] + red[1] + red[2] + red[3]) * (1.0f / C_);
        return;
    }
    int ci = t & 15, dr = t >> 4;                    // 16 col x 16 rowgroups
    int c = j * 16 + ci;
    float s = 0.f;
#pragma unroll 8
    for (int k = 0; k < 64; ++k)
        s += W[(size_t)(dr * 64 + k) * C_ + c];      // 64B segments per wave quarter
    __shared__ float sd[16][16];
    sd[dr][ci] = s;
    __syncthreads();
    if (t < 16) {
        float acc = 0.f;
#pragma unroll
        for (int d = 0; d < 16; ++d) acc += sd[d][t];
        ws[WS_WBAR + j * 16 + t] = acc * (1.0f / C_);
    }
}

// ---- scores: TWO rows per wave, 8 waves/block ; wbar in registers ----
__global__ __launch_bounds__(512) void scores_kernel(const float* __restrict__ x,
                                                     float* ws) {
    int t = threadIdx.x;
    int wave = t >> 6, lane = t & 63;
    const float4* wb4 = (const float4*)(ws + WS_WBAR);
    float4 wv0 = wb4[0 * 64 + lane];                 // 4KB wbar, L2-resident
    float4 wv1 = wb4[1 * 64 + lane];
    float4 wv2 = wb4[2 * 64 + lane];
    float4 wv3 = wb4[3 * 64 + lane];
    float bbar = ws[WS_BBAR];
    int row0 = blockIdx.x * 16 + wave * 2;           // two consecutive rows
    const vf4* x4 = (const vf4*)x;
    const vf4* pa = x4 + (size_t)row0 * 256 + lane;
    const vf4* pb = pa + 256;
    vf4 a0 = __builtin_nontemporal_load(pa + 0 * 64);
    vf4 a1 = __builtin_nontemporal_load(pa + 1 * 64);
    vf4 a2 = __builtin_nontemporal_load(pa + 2 * 64);
    vf4 a3 = __builtin_nontemporal_load(pa + 3 * 64);
    vf4 b0 = __builtin_nontemporal_load(pb + 0 * 64);
    vf4 b1 = __builtin_nontemporal_load(pb + 1 * 64);
    vf4 b2 = __builtin_nontemporal_load(pb + 2 * 64);
    vf4 b3 = __builtin_nontemporal_load(pb + 3 * 64);
    float accA = a0.x * wv0.x + a0.y * wv0.y + a0.z * wv0.z + a0.w * wv0.w
               + a1.x * wv1.x + a1.y * wv1.y + a1.z * wv1.z + a1.w * wv1.w
               + a2.x * wv2.x + a2.y * wv2.y + a2.z * wv2.z + a2.w * wv2.w
               + a3.x * wv3.x + a3.y * wv3.y + a3.z * wv3.z + a3.w * wv3.w;
    float accB = b0.x * wv0.x + b0.y * wv0.y + b0.z * wv0.z + b0.w * wv0.w
               + b1.x * wv1.x + b1.y * wv1.y + b1.z * wv1.z + b1.w * wv1.w
               + b2.x * wv2.x + b2.y * wv2.y + b2.z * wv2.z + b2.w * wv2.w
               + b3.x * wv3.x + b3.y * wv3.y + b3.z * wv3.z + b3.w * wv3.w;
    for (int off = 32; off; off >>= 1) {
        accA += __shfl_xor(accA, off);
        accB += __shfl_xor(accB, off);
    }
    if (lane == 0) {
        ws[WS_SCORES + row0 + 0] = accA + bbar;
        ws[WS_SCORES + row0 + 1] = accB + bbar;
    }
}

// sortable-uint mapping for f32 (monotonic)
__device__ __forceinline__ unsigned su_(float f) {
    unsigned u = __float_as_uint(f);
    return (u & 0x80000000u) ? ~u : (u | 0x80000000u);
}
__device__ __forceinline__ float isu_(unsigned u) {
    unsigned v = (u & 0x80000000u) ? (u ^ 0x80000000u) : ~u;
    return __uint_as_float(v);
}

// ---- 4 blocks per batch: each redundantly selects top-64, then owns a
//      256-col out slice and a 1024-entry mask slice (disjoint writes) ----
__global__ __launch_bounds__(256) void topk_out_kernel(const float* __restrict__ x,
                                                       const float* __restrict__ ws,
                                                       float* __restrict__ out,
                                                       float* __restrict__ mask_out) {
    __shared__ unsigned hist[4096];                 // 16 KB
    __shared__ unsigned long long cand[4096];       // 32 KB (worst-case capacity)
    __shared__ float redf[4];
    __shared__ unsigned scnt;
    __shared__ int sbin;
    __shared__ int   li[K_];
    __shared__ float la[K_];
    int blk = blockIdx.x;
    int b = blk >> 2, cc = blk & 3;
    int t = threadIdx.x;
    int wid = t >> 6, lane = t & 63;
    const float* srow = ws + WS_SCORES + b * N_;

    // thread owns indices i*1024 + 4t + e  (4 float4 loads)
    float v[16];
#pragma unroll
    for (int i = 0; i < 4; ++i) {
        float4 v4 = ((const float4*)srow)[i * 256 + t];
        v[i * 4 + 0] = v4.x; v[i * 4 + 1] = v4.y;
        v[i * 4 + 2] = v4.z; v[i * 4 + 3] = v4.w;
    }

#pragma unroll
    for (int e = 0; e < 16; ++e) hist[e * 256 + t] = 0;
    if (t == 0) scnt = 0;

    // global max
    float m = v[0];
#pragma unroll
    for (int e = 1; e < 16; ++e) m = fmaxf(m, v[e]);
    for (int off = 32; off; off >>= 1) m = fmaxf(m, __shfl_xor(m, off));
    if (lane == 0) redf[wid] = m;
    __syncthreads();                                // hist zeroed + redf(max) ready
    m = fmaxf(fmaxf(redf[0], redf[1]), fmaxf(redf[2], redf[3]));

    // softmax denominator over ALL N (reference: softmax then mask)
    float dsum = 0.f;
#pragma unroll
    for (int e = 0; e < 16; ++e) dsum += expf(v[e] - m);
    for (int off = 32; off; off >>= 1) dsum += __shfl_xor(dsum, off);

    // histogram of top-12 bits of sortable key
#pragma unroll
    for (int e = 0; e < 16; ++e) atomicAdd(&hist[su_(v[e]) >> 20], 1u);

    __syncthreads();                                // everyone done reading redf(max)
    if (lane == 0) redf[wid] = dsum;
    __syncthreads();                                // redf(denom) + hist ready
    float denom = redf[0] + redf[1] + redf[2] + redf[3];

    // wave 0: suffix scan over 4096 bins to find the rank-64 threshold bin
    if (wid == 0) {
        int base = lane * 64;
        unsigned s = 0;
        for (int j = 0; j < 64; ++j) s += hist[base + j];
        unsigned suf = s;                           // inclusive suffix over lane chunks
        for (int off = 1; off < 64; off <<= 1) {
            unsigned o = __shfl_down(suf, off);
            if (lane + off < 64) suf += o;
        }
        unsigned above = suf - s;                   // count in higher chunks
        if (above < (unsigned)K_ && above + s >= (unsigned)K_) {
            unsigned run = above;
            for (int j = 63; j >= 0; --j) {
                unsigned c = hist[base + j];
                if (run < (unsigned)K_ && run + c >= (unsigned)K_) sbin = base + j;
                run += c;
            }
        }
    }
    __syncthreads();                                // sbin ready
    int Bn = sbin;

    // collect candidates (bucket >= threshold bin); keys unique (idx in low bits)
#pragma unroll
    for (int i = 0; i < 4; ++i) {
#pragma unroll
        for (int e = 0; e < 4; ++e) {
            unsigned k32 = su_(v[i * 4 + e]);
            if ((int)(k32 >> 20) >= Bn) {
                unsigned idx = (unsigned)(i * 1024 + 4 * t + e);
                unsigned p = atomicAdd(&scnt, 1u);
                cand[p] = ((unsigned long long)k32 << 32) |
                          (unsigned long long)(0xFFFFFFFFu - idx);
            }
        }
    }
    // zero this block's 1024-entry mask slice (coalesced)
#pragma unroll
    for (int e = 0; e < 4; ++e)
        mask_out[b * N_ + cc * 1024 + e * 256 + t] = 0.0f;
    __syncthreads();                                // cand/scnt ready

    unsigned mc = scnt;
    for (unsigned i = t; i < mc; i += 256) {
        unsigned long long ki = cand[i];
        unsigned r = 0;
        for (unsigned j = 0; j < mc; ++j) r += (cand[j] > ki) ? 1u : 0u;
        if (r < (unsigned)K_) {                     // exact rank; tie -> lower idx wins
            unsigned widx = 0xFFFFFFFFu - (unsigned)(ki & 0xFFFFFFFFu);
            float sc = isu_((unsigned)(ki >> 32));
            li[r] = (int)widx;
            la[r] = expf(sc - m) / denom;
            if ((int)(widx >> 10) == cc)            // winner in this block's mask slice
                mask_out[b * N_ + widx] = 1.0f;
        }
    }
    __syncthreads();                                // li/la ready

    // gather this block's 256-col out slice
    int col = cc * 256 + t;
    float acc = 0.f;
#pragma unroll 8
    for (int r = 0; r < K_; ++r) {
        acc += la[r] * x[(size_t)(b * N_ + li[r]) * C_ + col];  // 1KB coalesced/row
    }
    out[b * C_ + col] = acc;
}

extern "C" void kernel_launch(void* const* d_in, const int* in_sizes, int n_in,
                              void* d_out, int out_size, void* d_ws, size_t ws_size,
                              hipStream_t stream) {
    const float* x = (const float*)d_in[0];   // (B,N,C) f32
    const float* W = (const float*)d_in[1];   // (C,C) f32
    const float* b = (const float*)d_in[2];   // (C,) f32
    float* out  = (float*)d_out;              // (B,C) then (B,N) mask
    float* mask = out + B_ * C_;
    float* ws   = (float*)d_ws;

    wbar_kernel    <<<65,           256, 0, stream>>>(W, b, ws);
    scores_kernel  <<<B_ * N_ / 16, 512, 0, stream>>>(x, ws);
    topk_out_kernel<<<B_ * 4,       256, 0, stream>>>(x, ws, out, mask);
}

// Round 10
// 58.993 us; speedup vs baseline: 9.9786x; 1.1194x over previous
//
#include <hip/hip_runtime.h>
#include <cstdint>

#define B_ 16
#define N_ 4096
#define C_ 1024
#define K_ 64

typedef float vf4 __attribute__((ext_vector_type(4)));

// ws float-index layout
#define WS_WBAR   0                    // 1024 f32
#define WS_BBAR   1024                 // 1 f32
#define WS_SCORES 2048                 // B*N f32

// ---- wbar in one kernel: 64 blocks x 16 columns each; block 64: bbar ----
__global__ __launch_bounds__(256) void wbar_kernel(const float* __restrict__ W,
                                                   const float* __restrict__ b,
                                                   float* __restrict__ ws) {
    int j = blockIdx.x, t = threadIdx.x;
    if (j == 64) {                                   // bbar = mean(b)
        float4 bv = ((const float4*)b)[t];
        float sb = bv.x + bv.y + bv.z + bv.w;
        for (int off = 32; off; off >>= 1) sb += __shfl_xor(sb, off);
        __shared__ float red[4];
        if ((t & 63) == 0) red[t >> 6] = sb;
        __syncthreads();
        if (t == 0) ws[WS_BBAR] = (red[0] + red[1] + red[2] + red[3]) * (1.0f / C_);
        return;
    }
    int ci = t & 15, dr = t >> 4;                    // 16 col x 16 rowgroups
    int c = j * 16 + ci;
    float s = 0.f;
#pragma unroll 8
    for (int k = 0; k < 64; ++k)
        s += W[(size_t)(dr * 64 + k) * C_ + c];      // 64B segments per wave quarter
    __shared__ float sd[16][16];
    sd[dr][ci] = s;
    __syncthreads();
    if (t < 16) {
        float acc = 0.f;
#pragma unroll
        for (int d = 0; d < 16; ++d) acc += sd[d][t];
        ws[WS_WBAR + j * 16 + t] = acc * (1.0f / C_);
    }
}

// ---- scores: one wave per row, 8 waves/block ; wbar in registers (R7 exact) ----
__global__ __launch_bounds__(512) void scores_kernel(const float* __restrict__ x,
                                                     float* ws) {
    int t = threadIdx.x;
    int wave = t >> 6, lane = t & 63;
    const float4* wb4 = (const float4*)(ws + WS_WBAR);
    float4 wv0 = wb4[0 * 64 + lane];                 // 4KB wbar, L2-resident
    float4 wv1 = wb4[1 * 64 + lane];
    float4 wv2 = wb4[2 * 64 + lane];
    float4 wv3 = wb4[3 * 64 + lane];
    float bbar = ws[WS_BBAR];
    int row = blockIdx.x * 8 + wave;                 // row in [0, B*N)
    const vf4* x4 = (const vf4*)x;
    vf4 xv0 = __builtin_nontemporal_load(x4 + (size_t)row * 256 + 0 * 64 + lane);
    vf4 xv1 = __builtin_nontemporal_load(x4 + (size_t)row * 256 + 1 * 64 + lane);
    vf4 xv2 = __builtin_nontemporal_load(x4 + (size_t)row * 256 + 2 * 64 + lane);
    vf4 xv3 = __builtin_nontemporal_load(x4 + (size_t)row * 256 + 3 * 64 + lane);
    float acc = xv0.x * wv0.x + xv0.y * wv0.y + xv0.z * wv0.z + xv0.w * wv0.w
              + xv1.x * wv1.x + xv1.y * wv1.y + xv1.z * wv1.z + xv1.w * wv1.w
              + xv2.x * wv2.x + xv2.y * wv2.y + xv2.z * wv2.z + xv2.w * wv2.w
              + xv3.x * wv3.x + xv3.y * wv3.y + xv3.z * wv3.z + xv3.w * wv3.w;
    for (int off = 32; off; off >>= 1) acc += __shfl_xor(acc, off);
    if (lane == 0) ws[WS_SCORES + row] = acc + bbar;
}

// sortable-uint mapping for f32 (monotonic)
__device__ __forceinline__ unsigned su_(float f) {
    unsigned u = __float_as_uint(f);
    return (u & 0x80000000u) ? ~u : (u | 0x80000000u);
}
__device__ __forceinline__ float isu_(unsigned u) {
    unsigned v = (u & 0x80000000u) ? (u ^ 0x80000000u) : ~u;
    return __uint_as_float(v);
}

// ---- 4 blocks per batch, 512 threads: redundant select (R8-verified body),
//      disjoint 1024-entry mask slice + 256-col out slice per block ----
__global__ __launch_bounds__(512) void topk_out_kernel(const float* __restrict__ x,
                                                       const float* __restrict__ ws,
                                                       float* __restrict__ out,
                                                       float* __restrict__ mask_out) {
    __shared__ unsigned hist[4096];                 // 16 KB
    __shared__ unsigned long long cand[4096];       // 32 KB
    __shared__ float redm[8], redd[8];
    __shared__ unsigned scnt;
    __shared__ int sbin;
    __shared__ int   li[K_];
    __shared__ float la[K_];
    __shared__ float gsum[256];
    int blk = blockIdx.x;
    int b = blk >> 2, cc = blk & 3;
    int t = threadIdx.x;
    int wave = t >> 6, lane = t & 63;
    const float* srow = ws + WS_SCORES + b * N_;

    // thread owns indices i*2048 + 4t + e  (2 float4 loads)
    float v[8];
#pragma unroll
    for (int i = 0; i < 2; ++i) {
        float4 v4 = ((const float4*)srow)[i * 512 + t];
        v[i * 4 + 0] = v4.x; v[i * 4 + 1] = v4.y;
        v[i * 4 + 2] = v4.z; v[i * 4 + 3] = v4.w;
    }
#pragma unroll
    for (int i = 0; i < 2; ++i)
        ((uint4*)hist)[i * 512 + t] = make_uint4(0u, 0u, 0u, 0u);
    if (t == 0) scnt = 0;

    // batch max
    float m = v[0];
#pragma unroll
    for (int e = 1; e < 8; ++e) m = fmaxf(m, v[e]);
    for (int off = 32; off; off >>= 1) m = fmaxf(m, __shfl_xor(m, off));
    if (lane == 0) redm[wave] = m;
    __syncthreads();                                // hist zeroed + redm ready
    m = redm[0];
#pragma unroll
    for (int i = 1; i < 8; ++i) m = fmaxf(m, redm[i]);

    // softmax denominator over ALL N (reference: softmax then mask)
    float dsum = 0.f;
#pragma unroll
    for (int e = 0; e < 8; ++e) dsum += expf(v[e] - m);
    for (int off = 32; off; off >>= 1) dsum += __shfl_xor(dsum, off);
    if (lane == 0) redd[wave] = dsum;

    // histogram of top-12 bits of sortable key
#pragma unroll
    for (int e = 0; e < 8; ++e) atomicAdd(&hist[su_(v[e]) >> 20], 1u);
    __syncthreads();                                // hist + redd ready
    float denom = redd[0];
#pragma unroll
    for (int i = 1; i < 8; ++i) denom += redd[i];

    // wave 0: suffix scan over 4096 bins for the rank-64 threshold bin
    if (wave == 0) {
        int base = lane * 64;
        unsigned s = 0;
        for (int j = 0; j < 64; ++j) s += hist[base + j];
        unsigned suf = s;                           // inclusive suffix over lane chunks
        for (int off = 1; off < 64; off <<= 1) {
            unsigned o = __shfl_down(suf, off);
            if (lane + off < 64) suf += o;
        }
        unsigned above = suf - s;                   // count in higher chunks
        if (above < (unsigned)K_ && above + s >= (unsigned)K_) {
            unsigned run = above;
            for (int j = 63; j >= 0; --j) {
                unsigned c = hist[base + j];
                if (run < (unsigned)K_ && run + c >= (unsigned)K_) sbin = base + j;
                run += c;
            }
        }
    }
    __syncthreads();                                // sbin ready
    int Bn = sbin;

    // collect candidates (keys unique: idx in low bits)
#pragma unroll
    for (int i = 0; i < 2; ++i) {
#pragma unroll
        for (int e = 0; e < 4; ++e) {
            unsigned k32 = su_(v[i * 4 + e]);
            if ((int)(k32 >> 20) >= Bn) {
                unsigned idx = (unsigned)(i * 2048 + 4 * t + e);
                unsigned p = atomicAdd(&scnt, 1u);
                cand[p] = ((unsigned long long)k32 << 32) |
                          (unsigned long long)(0xFFFFFFFFu - idx);
            }
        }
    }
    // zero this block's 1024-entry mask slice (coalesced)
#pragma unroll
    for (int i = 0; i < 2; ++i)
        mask_out[b * N_ + cc * 1024 + i * 512 + t] = 0.0f;
    __syncthreads();                                // cand/scnt ready

    unsigned mc = scnt;
    for (unsigned i = t; i < mc; i += 512) {
        unsigned long long ki = cand[i];
        unsigned r = 0;
        for (unsigned j = 0; j < mc; ++j) r += (cand[j] > ki) ? 1u : 0u;
        if (r < (unsigned)K_) {                     // exact rank; tie -> lower idx wins
            unsigned widx = 0xFFFFFFFFu - (unsigned)(ki & 0xFFFFFFFFu);
            float sc = isu_((unsigned)(ki >> 32));
            li[r] = (int)widx;
            la[r] = expf(sc - m) / denom;
            if ((int)(widx >> 10) == cc)            // winner in this block's mask slice
                mask_out[b * N_ + widx] = 1.0f;
        }
    }
    __syncthreads();                                // li/la ready

    // gather this block's 256-col out slice; rows split across thread halves
    int col = cc * 256 + (t & 255);
    int rh = t >> 8;
    float ga = 0.f;
#pragma unroll 8
    for (int r = rh * 32; r < rh * 32 + 32; ++r)
        ga += la[r] * x[(size_t)(b * N_ + li[r]) * C_ + col];  // 1KB coalesced/row
    if (rh) gsum[t & 255] = ga;
    __syncthreads();
    if (!rh) out[b * C_ + col] = ga + gsum[t];
}

extern "C" void kernel_launch(void* const* d_in, const int* in_sizes, int n_in,
                              void* d_out, int out_size, void* d_ws, size_t ws_size,
                              hipStream_t stream) {
    const float* x = (const float*)d_in[0];   // (B,N,C) f32
    const float* W = (const float*)d_in[1];   // (C,C) f32
    const float* b = (const float*)d_in[2];   // (C,) f32
    float* out  = (float*)d_out;              // (B,C) then (B,N) mask
    float* mask = out + B_ * C_;
    float* ws   = (float*)d_ws;

    wbar_kernel    <<<65,          256, 0, stream>>>(W, b, ws);
    scores_kernel  <<<B_ * N_ / 8, 512, 0, stream>>>(x, ws);
    topk_out_kernel<<<B_ * 4,      512, 0, stream>>>(x, ws, out, mask);
}